// Round 11
// baseline (196.387 us; speedup 1.0000x reference)
//
#include <hip/hip_runtime.h>
#include <hip/hip_fp16.h>

// Fused 3D local-NCC loss. Shapes (2,1,160,192,160) fp32,
// flat = ((n*D + d)*H + h)*W + w. 9x9x9 box window, zero-padded.
//
// v11: two-kernel split with fp16 global intermediate (5-ch HW-sums).
//  K1 k_wh : per plane, W-slide (registers) -> LDS -> H-slide (float2) ->
//            v_cvt_pkrtz fp16 pack -> global. No D-ring, no reduction.
//  K2 k_dcc: no LDS/barriers; thread per (n,h,w,d-chunk) streams 27 planes
//            of fp16 HW-sums (coalesced u16), fp32 9-deep static D-ring,
//            cc, block reduce, pre-scaled atomicAdd.
// fp16 safe: sums in [0,81]; RTZ relative bias cancels in cc ratio
// (v7 measured absmax 0.0 with fp16 intermediates).
// Fallback: if ws_size < 98.3 MB, run the proven v8 single kernel.

namespace {
constexpr int Wd = 160, Hd = 192, Dd = 160, NB = 2;
constexpr long DSTRIDE = (long)Hd * Wd;        // 30720
constexpr long VOLUME  = (long)Dd * DSTRIDE;   // 4,915,200
constexpr long TOTAL   = VOLUME * NB;          // 9,830,400
constexpr float INV_WV = 1.0f / 729.0f;
constexpr float NEG_INV_TOTAL = -1.0f / 9830400.0f;

// K1 geometry: 32(w) x 24(h) tile, 8-plane d-chunk.
constexpr int BW1 = 32, BH1 = 24, EH1 = 32, DC1 = 8;
constexpr int WT1 = 5, HT1 = 8, NDC1 = 20;
constexpr int NBLK1 = NB * NDC1 * HT1 * WT1;   // 1600
constexpr int CH1 = EH1 * BW1;                 // 1024 floats / channel

// K2 geometry: 19 outputs per 27-plane march (3x9 for static ring).
constexpr int DK2 = 19, NCH2 = 9;              // 9*19=171 covers 160
constexpr int NBLK2 = (int)((long)NB * NCH2 * Hd * Wd / 256);  // 2160

// v8 fallback geometry.
constexpr int BWf = 32, BHf = 16, EHf = 24;
constexpr int NWBf = 5, NHBf = 12, NDBf = 9;
constexpr int NBLKf = NB * NDBf * NHBf * NWBf; // 1080
constexpr int CHf  = EHf * BWf;                // 768
constexpr int HWCf = BHf * BWf;                // 512
constexpr int NPLf = 27;

constexpr size_t WS_NEEDED = (size_t)5 * (size_t)TOTAL * 2;  // 98,304,000 B
}

typedef _Float16 half2v __attribute__((ext_vector_type(2)));

__device__ __forceinline__ void bar_lds() {
    asm volatile("s_waitcnt lgkmcnt(0)\n\ts_barrier" ::: "memory");
}

__device__ __forceinline__ float4 slide9(float v0, float v1, float v2, float v3,
                                         float v4, float v5, float v6, float v7,
                                         float v8, float v9, float v10, float v11) {
    float s8 = ((v0 + v1) + (v2 + v3)) + ((v4 + v5) + (v6 + v7)) + v8;
    float4 o;
    o.x = s8;
    o.y = o.x + (v9 - v0);
    o.z = o.y + (v10 - v1);
    o.w = o.z + (v11 - v2);
    return o;
}

__device__ __forceinline__ unsigned int pk32(float lo, float hi) {
    half2v h = (half2v)__builtin_amdgcn_cvt_pkrtz(lo, hi);
    return __builtin_bit_cast(unsigned int, h);
}

// ---------------------------------------------------------------------------
// K1: W-slide + H-slide -> fp16 global intermediate [5][NB][D][H][W]
// ---------------------------------------------------------------------------
__global__ __launch_bounds__(256) void k_wh(const float* __restrict__ I,
                                            const float* __restrict__ J,
                                            unsigned int* __restrict__ hwOut) {
    __shared__ float ws[5 * CH1];   // 20,480 B

    const int tid = threadIdx.x;
    int bx = blockIdx.x;
    const int wt = bx % WT1; bx /= WT1;
    const int ht = bx % HT1; bx /= HT1;
    const int dc = bx % NDC1; bx /= NDC1;
    const int n  = bx;
    const int w0 = wt * BW1, h0 = ht * BH1, d0 = dc * DC1;
    const long nvol = (long)n * VOLUME;

    // Stage-A mapping: all 256 threads, 32 rows x 8 four-wide segments.
    const int seg = tid & 7;
    const int yy  = tid >> 3;                  // 0..31
    const int ah  = h0 - 4 + yy;
    const int wbase = w0 - 4 + (seg << 2);
    const bool ahOk = ((unsigned)ah < (unsigned)Hd);
    const bool qok0 = ((unsigned)(wbase + 0) < (unsigned)Wd);
    const bool qok1 = ((unsigned)(wbase + 4) < (unsigned)Wd);
    const bool qok2 = ((unsigned)(wbase + 8) < (unsigned)Wd);
    const float* aI = I + nvol + (long)ah * Wd + wbase + (long)d0 * DSTRIDE;
    const float* aJ = J + nvol + (long)ah * Wd + wbase + (long)d0 * DSTRIDE;

    // Stage-A2 mapping (tid < 160): 5 ch x 2 h-halves x 16 float2 lanes.
    const int c2 = tid >> 5;                   // 0..4
    const int h2 = (tid >> 4) & 1;             // 0..1
    const int wp = tid & 15;                   // 0..15
    const float2* const a2src = (const float2*)(ws + c2 * CH1) + (h2 * 12) * 16 + wp;
    long obase = ((long)c2 * TOTAL + nvol + (long)d0 * DSTRIDE
                  + (long)(h0 + h2 * 12) * Wd + w0) / 2 + wp;   // u32 index

    float4 pI0, pI1, pI2, pJ0, pJ1, pJ2;

#define ISSUE()                                                             \
    do {                                                                    \
        pI0 = (ahOk && qok0) ? *(const float4*)(aI + 0) : float4{0, 0, 0, 0}; \
        pI1 = (ahOk && qok1) ? *(const float4*)(aI + 4) : float4{0, 0, 0, 0}; \
        pI2 = (ahOk && qok2) ? *(const float4*)(aI + 8) : float4{0, 0, 0, 0}; \
        pJ0 = (ahOk && qok0) ? *(const float4*)(aJ + 0) : float4{0, 0, 0, 0}; \
        pJ1 = (ahOk && qok1) ? *(const float4*)(aJ + 4) : float4{0, 0, 0, 0}; \
        pJ2 = (ahOk && qok2) ? *(const float4*)(aJ + 8) : float4{0, 0, 0, 0}; \
    } while (0)

    ISSUE();   // prime plane d0

#pragma unroll 1
    for (int pp = 0; pp < DC1; ++pp) {
        // -------- Stage A: consume prefetch -> W-slide -> LDS ------------
        {
            const float a0 = pI0.x, a1 = pI0.y, a2 = pI0.z, a3 = pI0.w;
            const float a4 = pI1.x, a5 = pI1.y, a6 = pI1.z, a7 = pI1.w;
            const float a8 = pI2.x, a9 = pI2.y, a10 = pI2.z, a11 = pI2.w;
            const float b0 = pJ0.x, b1 = pJ0.y, b2 = pJ0.z, b3 = pJ0.w;
            const float b4 = pJ1.x, b5 = pJ1.y, b6 = pJ1.z, b7 = pJ1.w;
            const float b8 = pJ2.x, b9 = pJ2.y, b10 = pJ2.z, b11 = pJ2.w;
            float* const wab = ws + yy * BW1 + (seg << 2);
            *(float4*)(wab + 0 * CH1) =
                slide9(a0, a1, a2, a3, a4, a5, a6, a7, a8, a9, a10, a11);
            *(float4*)(wab + 1 * CH1) =
                slide9(b0, b1, b2, b3, b4, b5, b6, b7, b8, b9, b10, b11);
            *(float4*)(wab + 2 * CH1) =
                slide9(a0 * a0, a1 * a1, a2 * a2, a3 * a3, a4 * a4, a5 * a5,
                       a6 * a6, a7 * a7, a8 * a8, a9 * a9, a10 * a10, a11 * a11);
            *(float4*)(wab + 3 * CH1) =
                slide9(b0 * b0, b1 * b1, b2 * b2, b3 * b3, b4 * b4, b5 * b5,
                       b6 * b6, b7 * b7, b8 * b8, b9 * b9, b10 * b10, b11 * b11);
            *(float4*)(wab + 4 * CH1) =
                slide9(a0 * b0, a1 * b1, a2 * b2, a3 * b3, a4 * b4, a5 * b5,
                       a6 * b6, a7 * b7, a8 * b8, a9 * b9, a10 * b10, a11 * b11);
        }
        aI += DSTRIDE; aJ += DSTRIDE;
        if (pp < DC1 - 1) { ISSUE(); }

        bar_lds();

        // -------- Stage A2: float2 H-slide -> fp16 pack -> global --------
        if (tid < 160) {
            const float2* const src = a2src;
            unsigned int* const o = hwOut + obase;
            float2 g0 = src[0 * 16], g1 = src[1 * 16];
            float2 g2 = src[2 * 16], g3 = src[3 * 16];
            float2 g4 = src[4 * 16], g5 = src[5 * 16];
            float2 g6 = src[6 * 16], g7 = src[7 * 16];
            float2 s;
            s.x = ((g0.x + g1.x) + (g2.x + g3.x)) + ((g4.x + g5.x) + (g6.x + g7.x));
            s.y = ((g0.y + g1.y) + (g2.y + g3.y)) + ((g4.y + g5.y) + (g6.y + g7.y));
            float2 r, h8, h9, h10;
            r = src[ 8 * 16]; h8 = r;
            s.x += r.x; s.y += r.y; o[ 0 * 80] = pk32(s.x, s.y); s.x -= g0.x; s.y -= g0.y;
            r = src[ 9 * 16]; h9 = r;
            s.x += r.x; s.y += r.y; o[ 1 * 80] = pk32(s.x, s.y); s.x -= g1.x; s.y -= g1.y;
            r = src[10 * 16]; h10 = r;
            s.x += r.x; s.y += r.y; o[ 2 * 80] = pk32(s.x, s.y); s.x -= g2.x; s.y -= g2.y;
            r = src[11 * 16];
            s.x += r.x; s.y += r.y; o[ 3 * 80] = pk32(s.x, s.y); s.x -= g3.x; s.y -= g3.y;
            r = src[12 * 16];
            s.x += r.x; s.y += r.y; o[ 4 * 80] = pk32(s.x, s.y); s.x -= g4.x; s.y -= g4.y;
            r = src[13 * 16];
            s.x += r.x; s.y += r.y; o[ 5 * 80] = pk32(s.x, s.y); s.x -= g5.x; s.y -= g5.y;
            r = src[14 * 16];
            s.x += r.x; s.y += r.y; o[ 6 * 80] = pk32(s.x, s.y); s.x -= g6.x; s.y -= g6.y;
            r = src[15 * 16];
            s.x += r.x; s.y += r.y; o[ 7 * 80] = pk32(s.x, s.y); s.x -= g7.x; s.y -= g7.y;
            r = src[16 * 16];
            s.x += r.x; s.y += r.y; o[ 8 * 80] = pk32(s.x, s.y); s.x -= h8.x; s.y -= h8.y;
            r = src[17 * 16];
            s.x += r.x; s.y += r.y; o[ 9 * 80] = pk32(s.x, s.y); s.x -= h9.x; s.y -= h9.y;
            r = src[18 * 16];
            s.x += r.x; s.y += r.y; o[10 * 80] = pk32(s.x, s.y); s.x -= h10.x; s.y -= h10.y;
            r = src[19 * 16];
            s.x += r.x; s.y += r.y; o[11 * 80] = pk32(s.x, s.y);
        }
        obase += DSTRIDE / 2;

        bar_lds();
    }
#undef ISSUE
}

// ---------------------------------------------------------------------------
// K2: stream fp16 HW-sums, fp32 D-ring, cc, reduce.
// ---------------------------------------------------------------------------
__global__ __launch_bounds__(256) void k_dcc(const unsigned short* __restrict__ hwIn,
                                             float* __restrict__ out) {
    const int tid = threadIdx.x;
    long gid = (long)blockIdx.x * 256 + tid;
    const int w = (int)(gid % Wd); gid /= Wd;
    const int h = (int)(gid % Hd); gid /= Hd;
    const int ck = (int)(gid % NCH2); gid /= NCH2;
    const int n = (int)gid;
    const int d0 = ck * DK2;
    const long cbase = (long)n * VOLUME + (long)h * Wd + w;  // u16 idx, ch 0, d 0

    float hist[9][5];
#pragma unroll
    for (int k = 0; k < 9; ++k)
#pragma unroll
        for (int c = 0; c < 5; ++c) hist[k][c] = 0.0f;
    float sa[5] = {0, 0, 0, 0, 0};
    float acc = 0.0f;

#pragma unroll 1
    for (int M = 0; M < 3; ++M) {
#pragma unroll
        for (int u = 0; u < 9; ++u) {
            const int t = 9 * M + u;
            const int p = d0 - 4 + t;
            float h5[5];
            if ((unsigned)p < (unsigned)Dd) {
                const long idx = cbase + (long)p * DSTRIDE;
#pragma unroll
                for (int c = 0; c < 5; ++c) {
                    const unsigned short v = hwIn[idx + (long)c * TOTAL];
                    h5[c] = (float)__builtin_bit_cast(_Float16, v);
                }
            } else {
#pragma unroll
                for (int c = 0; c < 5; ++c) h5[c] = 0.0f;
            }
#pragma unroll
            for (int c = 0; c < 5; ++c) sa[c] += h5[c];
            const int dout = d0 + t - 8;
            if (t >= 8 && dout < Dd) {
                const float cross = sa[4] - sa[0] * sa[1] * INV_WV;
                const float iv    = sa[2] - sa[0] * sa[0] * INV_WV;
                const float jv    = sa[3] - sa[1] * sa[1] * INV_WV;
                acc += (cross * cross) * __builtin_amdgcn_rcpf(iv * jv + 1e-5f);
            }
#pragma unroll
            for (int c = 0; c < 5; ++c) sa[c] -= hist[(u + 1) % 9][c];
#pragma unroll
            for (int c = 0; c < 5; ++c) hist[u][c] = h5[c];
        }
    }

    __shared__ float red[256];
    red[tid] = acc;
    __syncthreads();
    for (int off = 128; off > 0; off >>= 1) {
        if (tid < off) red[tid] += red[tid + off];
        __syncthreads();
    }
    if (tid == 0) atomicAdd(out, red[0] * NEG_INV_TOTAL);
}

// ---------------------------------------------------------------------------
// Fallback: proven v8 single kernel (81 us) if workspace is too small.
// ---------------------------------------------------------------------------
__global__ __launch_bounds__(512) void k_fused(const float* __restrict__ I,
                                               const float* __restrict__ J,
                                               float* __restrict__ out) {
    __shared__ float ws[5 * CHf];
    __shared__ float hw[5 * HWCf];
    __shared__ float red[512];

    const int tid = threadIdx.x;
    int bx = blockIdx.x;
    const int wb = bx % NWBf; bx /= NWBf;
    const int hb = bx % NHBf; bx /= NHBf;
    const int db = bx % NDBf; bx /= NDBf;
    const int n  = bx;
    const int w0 = wb * BWf, h0 = hb * BHf, d0 = db * 19;
    const long nvol = (long)n * VOLUME;

    const int seg = tid & 7;
    const int yy  = tid >> 3;
    const bool aJob = (tid < 192);
    const int ah    = h0 - 4 + yy;
    const int wbase = w0 - 4 + (seg << 2);
    const bool ahOk = aJob && ((unsigned)ah < (unsigned)Hd);
    const bool qok0 = ((unsigned)(wbase + 0) < (unsigned)Wd);
    const bool qok1 = ((unsigned)(wbase + 4) < (unsigned)Wd);
    const bool qok2 = ((unsigned)(wbase + 8) < (unsigned)Wd);
    const long roff = nvol + (long)ah * Wd + wbase + (long)(d0 - 4) * DSTRIDE;
    const float* aI = I + roff;
    const float* aJ = J + roff;

    const int c2 = tid >> 5;
    const int wp = tid & 15;
    const int hq = (tid >> 4) & 1;
    const float2* const a2src = (const float2*)(ws + c2 * CHf) + (hq * 8) * 16 + wp;
    float2* const a2dst = (float2*)(hw + c2 * HWCf) + (hq * 8) * 16 + wp;

    const int tx = tid & 31, ty = tid >> 5;

    float4 pI0, pI1, pI2, pJ0, pJ1, pJ2;

#define ISSUEF(PP)                                                           \
    do {                                                                     \
        const bool _pv = ahOk && ((unsigned)(PP) < (unsigned)Dd);            \
        pI0 = (_pv && qok0) ? *(const float4*)(aI + 0) : float4{0, 0, 0, 0}; \
        pI1 = (_pv && qok1) ? *(const float4*)(aI + 4) : float4{0, 0, 0, 0}; \
        pI2 = (_pv && qok2) ? *(const float4*)(aI + 8) : float4{0, 0, 0, 0}; \
        pJ0 = (_pv && qok0) ? *(const float4*)(aJ + 0) : float4{0, 0, 0, 0}; \
        pJ1 = (_pv && qok1) ? *(const float4*)(aJ + 4) : float4{0, 0, 0, 0}; \
        pJ2 = (_pv && qok2) ? *(const float4*)(aJ + 8) : float4{0, 0, 0, 0}; \
    } while (0)

    float hist[9][5];
#pragma unroll
    for (int k = 0; k < 9; ++k)
#pragma unroll
        for (int c = 0; c < 5; ++c) hist[k][c] = 0.0f;
    float sa[5] = {0, 0, 0, 0, 0};
    float acc = 0.0f;

    ISSUEF(d0 - 4);

#pragma unroll 1
    for (int M = 0; M < 3; ++M) {
#pragma unroll
        for (int u = 0; u < 9; ++u) {
            const int t = 9 * M + u;
            const int p = d0 - 4 + t;
            const bool pvalid = ((unsigned)p < (unsigned)Dd);

            if (pvalid && aJob) {
                const float a0 = pI0.x, a1 = pI0.y, a2 = pI0.z, a3 = pI0.w;
                const float a4 = pI1.x, a5 = pI1.y, a6 = pI1.z, a7 = pI1.w;
                const float a8 = pI2.x, a9 = pI2.y, a10 = pI2.z, a11 = pI2.w;
                const float b0 = pJ0.x, b1 = pJ0.y, b2 = pJ0.z, b3 = pJ0.w;
                const float b4 = pJ1.x, b5 = pJ1.y, b6 = pJ1.z, b7 = pJ1.w;
                const float b8 = pJ2.x, b9 = pJ2.y, b10 = pJ2.z, b11 = pJ2.w;
                float* const wab = ws + yy * BWf + (seg << 2);
                *(float4*)(wab + 0 * CHf) =
                    slide9(a0, a1, a2, a3, a4, a5, a6, a7, a8, a9, a10, a11);
                *(float4*)(wab + 1 * CHf) =
                    slide9(b0, b1, b2, b3, b4, b5, b6, b7, b8, b9, b10, b11);
                *(float4*)(wab + 2 * CHf) =
                    slide9(a0 * a0, a1 * a1, a2 * a2, a3 * a3, a4 * a4, a5 * a5,
                           a6 * a6, a7 * a7, a8 * a8, a9 * a9, a10 * a10, a11 * a11);
                *(float4*)(wab + 3 * CHf) =
                    slide9(b0 * b0, b1 * b1, b2 * b2, b3 * b3, b4 * b4, b5 * b5,
                           b6 * b6, b7 * b7, b8 * b8, b9 * b9, b10 * b10, b11 * b11);
                *(float4*)(wab + 4 * CHf) =
                    slide9(a0 * b0, a1 * b1, a2 * b2, a3 * b3, a4 * b4, a5 * b5,
                           a6 * b6, a7 * b7, a8 * b8, a9 * b9, a10 * b10, a11 * b11);
            }
            aI += DSTRIDE; aJ += DSTRIDE;
            if (t < 26) { ISSUEF(p + 1); }

            bar_lds();

            if (pvalid && tid < 160) {
                const float2* const src = a2src;
                float2* const dst = a2dst;
                const float2 g0 = src[0 * 16], g1 = src[1 * 16];
                const float2 g2 = src[2 * 16], g3 = src[3 * 16];
                const float2 g4 = src[4 * 16], g5 = src[5 * 16];
                const float2 g6 = src[6 * 16], g7 = src[7 * 16];
                float2 s;
                s.x = ((g0.x + g1.x) + (g2.x + g3.x)) + ((g4.x + g5.x) + (g6.x + g7.x));
                s.y = ((g0.y + g1.y) + (g2.y + g3.y)) + ((g4.y + g5.y) + (g6.y + g7.y));
                float2 r;
                r = src[ 8 * 16]; s.x += r.x; s.y += r.y; dst[0 * 16] = s; s.x -= g0.x; s.y -= g0.y;
                r = src[ 9 * 16]; s.x += r.x; s.y += r.y; dst[1 * 16] = s; s.x -= g1.x; s.y -= g1.y;
                r = src[10 * 16]; s.x += r.x; s.y += r.y; dst[2 * 16] = s; s.x -= g2.x; s.y -= g2.y;
                r = src[11 * 16]; s.x += r.x; s.y += r.y; dst[3 * 16] = s; s.x -= g3.x; s.y -= g3.y;
                r = src[12 * 16]; s.x += r.x; s.y += r.y; dst[4 * 16] = s; s.x -= g4.x; s.y -= g4.y;
                r = src[13 * 16]; s.x += r.x; s.y += r.y; dst[5 * 16] = s; s.x -= g5.x; s.y -= g5.y;
                r = src[14 * 16]; s.x += r.x; s.y += r.y; dst[6 * 16] = s; s.x -= g6.x; s.y -= g6.y;
                r = src[15 * 16]; s.x += r.x; s.y += r.y; dst[7 * 16] = s;
            }

            bar_lds();

            float h5[5];
            if (pvalid) {
#pragma unroll
                for (int c = 0; c < 5; ++c)
                    h5[c] = hw[c * HWCf + ty * BWf + tx];
            } else {
#pragma unroll
                for (int c = 0; c < 5; ++c) h5[c] = 0.0f;
            }
#pragma unroll
            for (int c = 0; c < 5; ++c) sa[c] += h5[c];
            const int dout = d0 + t - 8;
            if (t >= 8 && dout < Dd) {
                const float cross = sa[4] - sa[0] * sa[1] * INV_WV;
                const float iv    = sa[2] - sa[0] * sa[0] * INV_WV;
                const float jv    = sa[3] - sa[1] * sa[1] * INV_WV;
                acc += (cross * cross) * __builtin_amdgcn_rcpf(iv * jv + 1e-5f);
            }
#pragma unroll
            for (int c = 0; c < 5; ++c) sa[c] -= hist[(u + 1) % 9][c];
#pragma unroll
            for (int c = 0; c < 5; ++c) hist[u][c] = h5[c];
        }
    }
#undef ISSUEF

    red[tid] = acc;
    __syncthreads();
    for (int off = 256; off > 0; off >>= 1) {
        if (tid < off) red[tid] += red[tid + off];
        __syncthreads();
    }
    if (tid == 0) atomicAdd(out, red[0] * NEG_INV_TOTAL);
}

extern "C" void kernel_launch(void* const* d_in, const int* in_sizes, int n_in,
                              void* d_out, int out_size, void* d_ws, size_t ws_size,
                              hipStream_t stream) {
    const float* I = (const float*)d_in[0];
    const float* J = (const float*)d_in[1];
    float* out = (float*)d_out;

    hipMemsetAsync(d_out, 0, sizeof(float), stream);   // stream-ordered, graph-safe
    if (ws_size >= WS_NEEDED) {
        k_wh<<<NBLK1, 256, 0, stream>>>(I, J, (unsigned int*)d_ws);
        k_dcc<<<NBLK2, 256, 0, stream>>>((const unsigned short*)d_ws, out);
    } else {
        k_fused<<<NBLKf, 512, 0, stream>>>(I, J, out);
    }
}